// Round 10
// baseline (4146.136 us; speedup 1.0000x reference)
//
#include <hip/hip_runtime.h>
#include <math.h>

#define B_ 4
#define S_ 2048
#define D_ 1024
#define F_ 4096
#define E_ 8
#define T_ 8192
#define LBW_ 0.01f
#define HROWS_ 17408   // sum of per-expert 128-padded counts <= 16384 + 8*127
#define NTILE_MAX 72   // max total 256-row M-tiles across experts

typedef unsigned short u16;
typedef __attribute__((ext_vector_type(8))) short bf16x8;
typedef __attribute__((ext_vector_type(4))) float f32x4;

#define GLOAD16(gp, lp) __builtin_amdgcn_global_load_lds( \
    (const __attribute__((address_space(1))) void*)(gp),  \
    (__attribute__((address_space(3))) void*)(lp), 16, 0, 0)

__device__ __forceinline__ u16 f2b(float f) {
    unsigned u = __float_as_uint(f);
    u = (u + 0x7FFFu + ((u >> 16) & 1u)) >> 16;   // RNE f32 -> bf16
    return (u16)u;
}
__device__ __forceinline__ float gelu_f(float v) {
    return 0.5f * v * (1.0f + erff(v * 0.70710678118654752440f));
}

// ------- per-expert transpose + convert: src (R x C f32) -> dst (C x R bf16) -------
__global__ __launch_bounds__(256) void cvt_T_kernel(const float* __restrict__ src,
                                                    u16* __restrict__ dst, int R, int C) {
    __shared__ u16 t[64][72];
    const int e = blockIdx.z;
    const float* s = src + (size_t)e * R * C;
    u16* d = dst + (size_t)e * R * C;
    const int r0 = blockIdx.y * 64, c0 = blockIdx.x * 64;
    const int tid = threadIdx.x;
    {
        int rr = tid >> 2, cq = (tid & 3) * 16;
        #pragma unroll
        for (int j = 0; j < 16; j += 4) {
            float4 v = *(const float4*)(s + (size_t)(r0 + rr) * C + c0 + cq + j);
            t[cq + j + 0][rr] = f2b(v.x);
            t[cq + j + 1][rr] = f2b(v.y);
            t[cq + j + 2][rr] = f2b(v.z);
            t[cq + j + 3][rr] = f2b(v.w);
        }
    }
    __syncthreads();
    {
        int cr = tid >> 2, rq = (tid & 3) * 16;
        #pragma unroll
        for (int j = 0; j < 16; j += 8) {
            int4 pk; u16* pw = (u16*)&pk;
            #pragma unroll
            for (int jj = 0; jj < 8; ++jj) pw[jj] = t[cr][rq + j + jj];
            *(int4*)(d + (size_t)(c0 + cr) * R + r0 + rq + j) = pk;
        }
    }
}

// ------- gate: f64 logits, softmax, top-2, routing lists, loss partials; also x->bf16 -------
__global__ __launch_bounds__(64) void gate_kernel(
    const float* __restrict__ x, const float* __restrict__ ew,
    const float* __restrict__ gw, const float* __restrict__ gb,
    u16* __restrict__ xb,
    float* __restrict__ combine, int* __restrict__ idx, int* __restrict__ cnt,
    int* __restrict__ fcnt, float* __restrict__ psum)
{
    const int t = blockIdx.x, l = threadIdx.x;
    const float* xr = x + (size_t)t * D_;
    double acc[E_];
    #pragma unroll
    for (int e = 0; e < E_; ++e) acc[e] = 0.0;
    u16 xw[16];
    #pragma unroll
    for (int kk = 0; kk < 16; kk += 4) {
        float4 xv = *(const float4*)(xr + l * 16 + kk);
        float xs[4] = {xv.x, xv.y, xv.z, xv.w};
        #pragma unroll
        for (int j = 0; j < 4; ++j) {
            xw[kk + j] = f2b(xs[j]);
            const float* gr = gw + (size_t)(l * 16 + kk + j) * E_;
            float4 g0 = *(const float4*)(gr);
            float4 g1 = *(const float4*)(gr + 4);
            acc[0] += (double)xs[j] * g0.x;  acc[1] += (double)xs[j] * g0.y;
            acc[2] += (double)xs[j] * g0.z;  acc[3] += (double)xs[j] * g0.w;
            acc[4] += (double)xs[j] * g1.x;  acc[5] += (double)xs[j] * g1.y;
            acc[6] += (double)xs[j] * g1.z;  acc[7] += (double)xs[j] * g1.w;
        }
    }
    *(int4*)(xb + (size_t)t * D_ + l * 16)     = *(int4*)(xw);
    *(int4*)(xb + (size_t)t * D_ + l * 16 + 8) = *(int4*)(xw + 8);
    #pragma unroll
    for (int e = 0; e < E_; ++e) {
        #pragma unroll
        for (int m = 32; m > 0; m >>= 1) acc[e] += __shfl_xor(acc[e], m);
    }
    if (l == 0) {
        const int b = t / S_;
        double p[E_]; double mx = -1e300;
        #pragma unroll
        for (int e = 0; e < E_; ++e) {
            p[e] = acc[e] + (double)gb[e] + (double)ew[b * E_ + e];
            mx = fmax(mx, p[e]);
        }
        double s = 0.0;
        #pragma unroll
        for (int e = 0; e < E_; ++e) { p[e] = exp(p[e] - mx); s += p[e]; }
        double inv = 1.0 / s;
        #pragma unroll
        for (int e = 0; e < E_; ++e) p[e] *= inv;
        double m1 = -1.0; int e1 = 0;
        #pragma unroll
        for (int e = 0; e < E_; ++e) if (p[e] > m1) { m1 = p[e]; e1 = e; }
        double m2 = -1.0; int e2 = 0;
        #pragma unroll
        for (int e = 0; e < E_; ++e) if (e != e1 && p[e] > m2) { m2 = p[e]; e2 = e; }
        float c1 = (float)(m1 / (m1 + m2)), c2 = (float)(m2 / (m1 + m2));
        #pragma unroll
        for (int e = 0; e < E_; ++e)
            combine[t * E_ + e] = (e == e1) ? c1 : ((e == e2) ? c2 : 0.0f);
        int q1 = atomicAdd(&cnt[e1], 1); idx[e1 * T_ + q1] = t;
        int q2 = atomicAdd(&cnt[e2], 1); idx[e2 * T_ + q2] = t;
        atomicAdd(&fcnt[(t & 63) * E_ + e1], 1);
        #pragma unroll
        for (int e = 0; e < E_; ++e) atomicAdd(&psum[(t & 63) * E_ + e], (float)p[e]);
    }
}

// ------- offsets + balanced M-tile table; off[E_] = total padded rows -------
__global__ void tiletab_kernel(const int* __restrict__ cnt, int* __restrict__ off,
                               int* __restrict__ table, int* __restrict__ ntab) {
    if (threadIdx.x == 0 && blockIdx.x == 0) {
        int o = 0, k = 0;
        for (int e = 0; e < E_; ++e) {
            off[e] = o;
            int pad = ((cnt[e] + 127) >> 7) << 7;
            o += pad;
            int nt = (pad + 255) >> 8;
            for (int i = 0; i < nt; ++i) table[k++] = e | (i << 4);
        }
        off[E_] = o;
        *ntab = k;
    }
}

// ------- gather routed token rows -> contiguous xg[slot] -------
__global__ __launch_bounds__(256) void gather_kernel(
    const u16* __restrict__ xb, const int* __restrict__ idx,
    const int* __restrict__ cnt, const int* __restrict__ off,
    u16* __restrict__ xg)
{
    const int r = blockIdx.x * 16 + (threadIdx.x >> 4);
    const int total = off[E_];
    if (r >= total) return;
    int e = 0;
    #pragma unroll
    for (int k = 1; k < E_; ++k) if (off[k] <= r) e = k;
    const int loc = r - off[e];
    const int cb = (threadIdx.x & 15) * 8;
    u16* dst = xg + (size_t)r * D_;
    if (loc < cnt[e]) {
        const u16* src = xb + (size_t)idx[e * T_ + loc] * D_;
        #pragma unroll
        for (int j = 0; j < 8; ++j)
            *(int4*)(dst + j * 128 + cb) = *(const int4*)(src + j * 128 + cb);
    } else {
        int4 z = {0, 0, 0, 0};
        #pragma unroll
        for (int j = 0; j < 8; ++j) *(int4*)(dst + j * 128 + cb) = z;
    }
}

// ---- 256x256 grouped GEMM, BK=32, DOUBLE buffer 64KB -> 2 blocks/CU (the fill-stream lever) ----
// Per-block gload_lds fill is capped ~10.4 B/cy (r3/r9 law); co-residency of 2 blocks doubles
// per-CU fill and makes barrier drains overlap (m114 mechanism). gemm2's ~272 blocks are ALL
// resident at once -> tail-quantization (r9's 2x) eliminated.
// Bank fix for 64B rows: half-wave (32-lane) LDS phase covers only 512B -> XOR slot by (row&3),
// both-sides (source-permuted gload per rule 21, swizzled read): exactly 4 accesses/bank/half-wave.
template<int NT, int KDROW, int NTN, bool IS_G1>
__global__ __launch_bounds__(512, 4) void moe_gemm2b(
    const u16* __restrict__ Aglob, const u16* __restrict__ Wt,
    const float* __restrict__ bias, const float* __restrict__ combine,
    const int* __restrict__ idxAll, const int* __restrict__ cntAll,
    const int* __restrict__ off, const int* __restrict__ table,
    const int* __restrict__ ntab,
    u16* __restrict__ hOut, float* __restrict__ out)
{
    const int gid = blockIdx.x;
    const int ti = gid % NTILE_MAX;          // ti fastest: balanced experts
    const int tn = gid / NTILE_MAX;
    if (ti >= *ntab) return;
    const int ent = table[ti];
    const int e = ent & 15, tm = ent >> 4;
    const int cnt = cntAll[e], base = off[e];
    const int* idx_e = idxAll + e * T_;
    const u16* Bsrc = Wt + (size_t)e * ((size_t)D_ * F_);

    __shared__ __align__(16) char lds[65536];    // 2 bufs x (A 16KB + B 16KB)

    const int tid = threadIdx.x;
    const int l = tid & 63, wid = tid >> 6;
    const int h = wid >> 2, g = wid & 3;         // wave tile 128x64 at (h*128, g*64)
    const int lr = l & 15, lg = l >> 4;

    // stage: wave wid owns chunks {2wid, 2wid+1}; chunk c = rows [16c,16c+16);
    // lane l -> row 16c+(l>>2); SOURCE k-chunk = (l&3)^((l>>2)&3) so LDS[r][slot q] = glob chunk q^(r&3)
    const int qsrc = ((l & 3) ^ ((l >> 2) & 3)) * 8;
    const u16* aP[2]; const u16* bP[2];
    #pragma unroll
    for (int i = 0; i < 2; ++i) {
        int c = 2 * wid + i;
        int hr = base + tm * 256 + c * 16 + (l >> 2);
        if (hr > HROWS_ - 1) hr = HROWS_ - 1;    // clamp tail straddle (pad rows zeroed)
        aP[i] = Aglob + (size_t)hr * KDROW + qsrc;
        int cc = tn * 256 + c * 16 + (l >> 2);
        bP[i] = Bsrc + (size_t)cc * KDROW + qsrc;
    }

    f32x4 acc[8][4];
    #pragma unroll
    for (int mi = 0; mi < 8; ++mi)
        #pragma unroll
        for (int ni = 0; ni < 4; ++ni) acc[mi][ni] = (f32x4){0.f,0.f,0.f,0.f};

    auto stage = [&](int buf, int kof) {
        char* bb = lds + buf * 32768;
        GLOAD16(aP[0] + kof, bb + (2 * wid) * 1024);
        GLOAD16(aP[1] + kof, bb + (2 * wid + 1) * 1024);
        GLOAD16(bP[0] + kof, bb + 16384 + (2 * wid) * 1024);
        GLOAD16(bP[1] + kof, bb + 16384 + (2 * wid + 1) * 1024);
    };

    stage(0, 0);
    asm volatile("s_waitcnt vmcnt(0)" ::: "memory");
    __builtin_amdgcn_s_barrier();

    const int koff = ((lg ^ (lr & 3)) << 4);     // read slot for k-chunk lg of row (row&3 == lr&3)
    for (int t = 0; t < NT; ++t) {
        const char* Ab = lds + (t & 1) * 32768;
        const char* Bb = Ab + 16384;
        bf16x8 a[8], b[4];
        #pragma unroll
        for (int mi = 0; mi < 8; ++mi)
            a[mi] = *(const bf16x8*)(Ab + (h * 128 + mi * 16 + lr) * 64 + koff);
        #pragma unroll
        for (int ni = 0; ni < 4; ++ni)
            b[ni] = *(const bf16x8*)(Bb + (g * 64 + ni * 16 + lr) * 64 + koff);
        if (t + 1 < NT) stage((t + 1) & 1, (t + 1) * 32);
        __builtin_amdgcn_s_setprio(1);
        #pragma unroll
        for (int mi = 0; mi < 8; ++mi)
            #pragma unroll
            for (int ni = 0; ni < 4; ++ni)
                acc[mi][ni] = __builtin_amdgcn_mfma_f32_16x16x32_bf16(a[mi], b[ni], acc[mi][ni], 0, 0, 0);
        __builtin_amdgcn_s_setprio(0);
        if (t + 1 < NT) {
            asm volatile("s_waitcnt vmcnt(0)" ::: "memory");
            __builtin_amdgcn_s_barrier();
        }
    }

    // ---- epilogue: C/D frag row = lg*4+j, col = lr ----
    const int wm = h * 128, wn = g * 64;
    if (IS_G1) {
        const float* be = bias + e * F_;
        const int pad = ((cnt + 127) >> 7) << 7;
        #pragma unroll
        for (int mi = 0; mi < 8; ++mi) {
            #pragma unroll
            for (int j = 0; j < 4; ++j) {
                int rl = tm * 256 + wm + mi * 16 + lg * 4 + j;
                if (rl < pad) {
                    size_t srow = (size_t)(base + rl) * F_;
                    #pragma unroll
                    for (int ni = 0; ni < 4; ++ni) {
                        int f = tn * 256 + wn + ni * 16 + lr;
                        hOut[srow + f] = f2b(gelu_f(acc[mi][ni][j] + be[f]));
                    }
                }
            }
        }
    } else {
        const float* be = bias + e * D_;
        #pragma unroll
        for (int mi = 0; mi < 8; ++mi) {
            #pragma unroll
            for (int j = 0; j < 4; ++j) {
                int rl = tm * 256 + wm + mi * 16 + lg * 4 + j;
                if (rl < cnt) {
                    int tkn = idx_e[rl];
                    float cw = combine[tkn * E_ + e];
                    float* orow = out + (size_t)tkn * D_;
                    #pragma unroll
                    for (int ni = 0; ni < 4; ++ni) {
                        int d = tn * 256 + wn + ni * 16 + lr;
                        atomicAdd(&orow[d], cw * (acc[mi][ni][j] + be[d]));
                    }
                }
            }
        }
    }
}

__global__ void loss_kernel(const int* __restrict__ fcnt, const float* __restrict__ psum,
                            float* __restrict__ dst) {
    if (threadIdx.x == 0 && blockIdx.x == 0) {
        float loss = 0.f;
        for (int e = 0; e < E_; ++e) {
            float fs = 0.f, Ps = 0.f;
            for (int s = 0; s < 64; ++s) { fs += (float)fcnt[s * E_ + e]; Ps += psum[s * E_ + e]; }
            loss += (fs / (float)T_) * (Ps / (float)T_);
        }
        *dst = LBW_ * (float)E_ * loss;
    }
}

__global__ void sentinel_kernel(float* __restrict__ dst) {
    if (threadIdx.x == 0) dst[0] = -12345.0f;
}

extern "C" void kernel_launch(void* const* d_in, const int* in_sizes, int n_in,
                              void* d_out, int out_size, void* d_ws, size_t ws_size,
                              hipStream_t stream)
{
    const float* x  = (const float*)d_in[0];
    const float* ew = (const float*)d_in[1];
    const float* gw = (const float*)d_in[2];
    const float* gb = (const float*)d_in[3];
    const float* w1 = (const float*)d_in[4];
    const float* b1 = (const float*)d_in[5];
    const float* w2 = (const float*)d_in[6];
    const float* b2 = (const float*)d_in[7];
    float* out = (float*)d_out;

    char* ws = (char*)d_ws;
    size_t o = 0;
    u16* w1t = (u16*)(ws + o); o += (size_t)E_ * D_ * F_ * 2;
    u16* w2t = (u16*)(ws + o); o += (size_t)E_ * F_ * D_ * 2;
    u16* xb  = (u16*)(ws + o); o += (size_t)T_ * D_ * 2;
    u16* xg  = (u16*)(ws + o); o += (size_t)HROWS_ * D_ * 2;
    u16* h   = (u16*)(ws + o); o += (size_t)HROWS_ * F_ * 2;
    float* combine = (float*)(ws + o); o += (size_t)T_ * E_ * 4;
    int* idx = (int*)(ws + o); o += (size_t)E_ * T_ * 4;
    size_t zoff = o;
    int* cnt   = (int*)(ws + o); o += 128;
    int* fcnt  = (int*)(ws + o); o += 64 * E_ * 4;
    float* psum = (float*)(ws + o); o += 64 * E_ * 4;
    int* off   = (int*)(ws + o); o += 128;
    int* table = (int*)(ws + o); o += 512;
    int* ntab  = (int*)(ws + o); o += 128;
    const size_t ws_needed = o;

    if (ws_size < ws_needed) {
        hipMemsetAsync(d_out, 0, (size_t)out_size * sizeof(float), stream);
        sentinel_kernel<<<1, 64, 0, stream>>>(out + (size_t)out_size - 1);
        return;
    }

    hipMemsetAsync(ws + zoff, 0, ws_needed - zoff, stream);
    hipMemsetAsync(d_out, 0, (size_t)out_size * sizeof(float), stream);

    cvt_T_kernel<<<dim3(F_ / 64, D_ / 64, E_), 256, 0, stream>>>(w1, w1t, D_, F_);
    cvt_T_kernel<<<dim3(D_ / 64, F_ / 64, E_), 256, 0, stream>>>(w2, w2t, F_, D_);
    gate_kernel<<<T_, 64, 0, stream>>>(x, ew, gw, gb, xb, combine, idx, cnt, fcnt, psum);
    tiletab_kernel<<<1, 64, 0, stream>>>(cnt, off, table, ntab);
    gather_kernel<<<HROWS_ / 16, 256, 0, stream>>>(xb, idx, cnt, off, xg);
    // gemm1: K=1024 (NT=32), 256x256, NTN=16 -> ~1088 working blocks at 2/CU = 2.13 rounds
    moe_gemm2b<32, 1024, 16, true><<<NTILE_MAX * 16, 512, 0, stream>>>(
        xg, w1t, b1, nullptr, idx, cnt, off, table, ntab, h, nullptr);
    // gemm2: K=4096 (NT=128), 256x256, NTN=4 -> ~272 working blocks, ALL co-resident at 2/CU
    moe_gemm2b<128, 4096, 4, false><<<NTILE_MAX * 4, 512, 0, stream>>>(
        h, w2t, b2, combine, idx, cnt, off, table, ntab, nullptr, out);
    loss_kernel<<<1, 64, 0, stream>>>(fcnt, psum, out + (size_t)out_size - 1);
}

// Round 11
// 841.579 us; speedup vs baseline: 4.9266x; 4.9266x over previous
//
#include <hip/hip_runtime.h>
#include <math.h>

#define B_ 4
#define S_ 2048
#define D_ 1024
#define F_ 4096
#define E_ 8
#define T_ 8192
#define LBW_ 0.01f
#define HROWS_ 17408   // sum of per-expert 128-padded counts <= 16384 + 8*127
#define NTILE_MAX 72   // max total 256-row M-tiles across experts

#define BUFB 24576     // LDS buffer: A 256x32x2 (16384) + B 128x32x2 (8192)

typedef unsigned short u16;
typedef __attribute__((ext_vector_type(8))) short bf16x8;
typedef __attribute__((ext_vector_type(4))) float f32x4;

#define GLOAD16(gp, lp) __builtin_amdgcn_global_load_lds( \
    (const __attribute__((address_space(1))) void*)(gp),  \
    (__attribute__((address_space(3))) void*)(lp), 16, 0, 0)

__device__ __forceinline__ u16 f2b(float f) {
    unsigned u = __float_as_uint(f);
    u = (u + 0x7FFFu + ((u >> 16) & 1u)) >> 16;   // RNE f32 -> bf16
    return (u16)u;
}
__device__ __forceinline__ float gelu_f(float v) {
    return 0.5f * v * (1.0f + erff(v * 0.70710678118654752440f));
}

// ------- per-expert transpose + convert: src (R x C f32) -> dst (C x R bf16) -------
__global__ __launch_bounds__(256) void cvt_T_kernel(const float* __restrict__ src,
                                                    u16* __restrict__ dst, int R, int C) {
    __shared__ u16 t[64][72];
    const int e = blockIdx.z;
    const float* s = src + (size_t)e * R * C;
    u16* d = dst + (size_t)e * R * C;
    const int r0 = blockIdx.y * 64, c0 = blockIdx.x * 64;
    const int tid = threadIdx.x;
    {
        int rr = tid >> 2, cq = (tid & 3) * 16;
        #pragma unroll
        for (int j = 0; j < 16; j += 4) {
            float4 v = *(const float4*)(s + (size_t)(r0 + rr) * C + c0 + cq + j);
            t[cq + j + 0][rr] = f2b(v.x);
            t[cq + j + 1][rr] = f2b(v.y);
            t[cq + j + 2][rr] = f2b(v.z);
            t[cq + j + 3][rr] = f2b(v.w);
        }
    }
    __syncthreads();
    {
        int cr = tid >> 2, rq = (tid & 3) * 16;
        #pragma unroll
        for (int j = 0; j < 16; j += 8) {
            int4 pk; u16* pw = (u16*)&pk;
            #pragma unroll
            for (int jj = 0; jj < 8; ++jj) pw[jj] = t[cr][rq + j + jj];
            *(int4*)(d + (size_t)(c0 + cr) * R + r0 + rq + j) = pk;
        }
    }
}

// ------- gate: f64 logits, softmax, top-2, routing lists, loss partials; also x->bf16 -------
__global__ __launch_bounds__(64) void gate_kernel(
    const float* __restrict__ x, const float* __restrict__ ew,
    const float* __restrict__ gw, const float* __restrict__ gb,
    u16* __restrict__ xb,
    float* __restrict__ combine, int* __restrict__ idx, int* __restrict__ cnt,
    int* __restrict__ fcnt, float* __restrict__ psum)
{
    const int t = blockIdx.x, l = threadIdx.x;
    const float* xr = x + (size_t)t * D_;
    double acc[E_];
    #pragma unroll
    for (int e = 0; e < E_; ++e) acc[e] = 0.0;
    u16 xw[16];
    #pragma unroll
    for (int kk = 0; kk < 16; kk += 4) {
        float4 xv = *(const float4*)(xr + l * 16 + kk);
        float xs[4] = {xv.x, xv.y, xv.z, xv.w};
        #pragma unroll
        for (int j = 0; j < 4; ++j) {
            xw[kk + j] = f2b(xs[j]);
            const float* gr = gw + (size_t)(l * 16 + kk + j) * E_;
            float4 g0 = *(const float4*)(gr);
            float4 g1 = *(const float4*)(gr + 4);
            acc[0] += (double)xs[j] * g0.x;  acc[1] += (double)xs[j] * g0.y;
            acc[2] += (double)xs[j] * g0.z;  acc[3] += (double)xs[j] * g0.w;
            acc[4] += (double)xs[j] * g1.x;  acc[5] += (double)xs[j] * g1.y;
            acc[6] += (double)xs[j] * g1.z;  acc[7] += (double)xs[j] * g1.w;
        }
    }
    *(int4*)(xb + (size_t)t * D_ + l * 16)     = *(int4*)(xw);
    *(int4*)(xb + (size_t)t * D_ + l * 16 + 8) = *(int4*)(xw + 8);
    #pragma unroll
    for (int e = 0; e < E_; ++e) {
        #pragma unroll
        for (int m = 32; m > 0; m >>= 1) acc[e] += __shfl_xor(acc[e], m);
    }
    if (l == 0) {
        const int b = t / S_;
        double p[E_]; double mx = -1e300;
        #pragma unroll
        for (int e = 0; e < E_; ++e) {
            p[e] = acc[e] + (double)gb[e] + (double)ew[b * E_ + e];
            mx = fmax(mx, p[e]);
        }
        double s = 0.0;
        #pragma unroll
        for (int e = 0; e < E_; ++e) { p[e] = exp(p[e] - mx); s += p[e]; }
        double inv = 1.0 / s;
        #pragma unroll
        for (int e = 0; e < E_; ++e) p[e] *= inv;
        double m1 = -1.0; int e1 = 0;
        #pragma unroll
        for (int e = 0; e < E_; ++e) if (p[e] > m1) { m1 = p[e]; e1 = e; }
        double m2 = -1.0; int e2 = 0;
        #pragma unroll
        for (int e = 0; e < E_; ++e) if (e != e1 && p[e] > m2) { m2 = p[e]; e2 = e; }
        float c1 = (float)(m1 / (m1 + m2)), c2 = (float)(m2 / (m1 + m2));
        #pragma unroll
        for (int e = 0; e < E_; ++e)
            combine[t * E_ + e] = (e == e1) ? c1 : ((e == e2) ? c2 : 0.0f);
        int q1 = atomicAdd(&cnt[e1], 1); idx[e1 * T_ + q1] = t;
        int q2 = atomicAdd(&cnt[e2], 1); idx[e2 * T_ + q2] = t;
        atomicAdd(&fcnt[(t & 63) * E_ + e1], 1);
        #pragma unroll
        for (int e = 0; e < E_; ++e) atomicAdd(&psum[(t & 63) * E_ + e], (float)p[e]);
    }
}

// ------- offsets + balanced M-tile table; off[E_] = total padded rows -------
__global__ void tiletab_kernel(const int* __restrict__ cnt, int* __restrict__ off,
                               int* __restrict__ table, int* __restrict__ ntab) {
    if (threadIdx.x == 0 && blockIdx.x == 0) {
        int o = 0, k = 0;
        for (int e = 0; e < E_; ++e) {
            off[e] = o;
            int pad = ((cnt[e] + 127) >> 7) << 7;
            o += pad;
            int nt = (pad + 255) >> 8;
            for (int i = 0; i < nt; ++i) table[k++] = e | (i << 4);
        }
        off[E_] = o;
        *ntab = k;
    }
}

// ------- gather routed token rows -> contiguous xg[slot] -------
__global__ __launch_bounds__(256) void gather_kernel(
    const u16* __restrict__ xb, const int* __restrict__ idx,
    const int* __restrict__ cnt, const int* __restrict__ off,
    u16* __restrict__ xg)
{
    const int r = blockIdx.x * 16 + (threadIdx.x >> 4);
    const int total = off[E_];
    if (r >= total) return;
    int e = 0;
    #pragma unroll
    for (int k = 1; k < E_; ++k) if (off[k] <= r) e = k;
    const int loc = r - off[e];
    const int cb = (threadIdx.x & 15) * 8;
    u16* dst = xg + (size_t)r * D_;
    if (loc < cnt[e]) {
        const u16* src = xb + (size_t)idx[e * T_ + loc] * D_;
        #pragma unroll
        for (int j = 0; j < 8; ++j)
            *(int4*)(dst + j * 128 + cb) = *(const int4*)(src + j * 128 + cb);
    } else {
        int4 z = {0, 0, 0, 0};
        #pragma unroll
        for (int j = 0; j < 8; ++j) *(int4*)(dst + j * 128 + cb) = z;
    }
}

// ---- 256x128 grouped GEMM, BK=32, 3-buffer lead-2 counted vmcnt(3), 2 BLOCKS/CU ----
// acc[4][4]=64 VGPR (r3 shape: 88 total) fits the 128-cap of __launch_bounds__(512,4);
// LDS 72KB -> 2 blocks/CU co-resident: doubles per-CU gload_lds fill streams and lets the
// sibling block cover each barrier drain (m114 overlap).
// Bank swizzle (derived r9/r10 post-mortem): collision axis is rows 4 apart (bank base
// 16*row mod 32, slot stride 4). Store: LDS[row][slot q] = global chunk q ^ ((row>>1)&3)
// via source perm qsrc=(l&3)^((l>>3)&3) (linear dest, rule 21). Read: slot = lg ^ ((lr>>1)&3).
// Tabulated: each 8-bank group gets exactly 4 of 32 half-wave accesses = optimal.
template<int NT, int KDROW, int NTN, bool IS_G1>
__global__ __launch_bounds__(512, 4) void moe_gemm2c(
    const u16* __restrict__ Aglob, const u16* __restrict__ Wt,
    const float* __restrict__ bias, const float* __restrict__ combine,
    const int* __restrict__ idxAll, const int* __restrict__ cntAll,
    const int* __restrict__ off, const int* __restrict__ table,
    const int* __restrict__ ntab,
    u16* __restrict__ hOut, float* __restrict__ out)
{
    const int gid = blockIdx.x;
    const int ti = gid % NTILE_MAX;          // ti fastest: balanced experts
    const int tn = gid / NTILE_MAX;
    if (ti >= *ntab) return;
    const int ent = table[ti];
    const int e = ent & 15, tm = ent >> 4;
    const int cnt = cntAll[e], base = off[e];
    const int* idx_e = idxAll + e * T_;
    const u16* Bsrc = Wt + (size_t)e * ((size_t)D_ * F_);

    __shared__ __align__(16) char lds[3 * BUFB];   // 3 bufs x (A 16KB + B 8KB) = 72KB

    const int tid = threadIdx.x;
    const int l = tid & 63, wid = tid >> 6;
    const int wm = (wid >> 1) * 64, wn = (wid & 1) * 64;   // wave tile 64x64 in 256x128
    const int lr = l & 15, lg = l >> 4;

    // stage: A = 16 chunks of 16 rows (wave wid owns {2wid, 2wid+1}); B = 8 chunks (wave owns wid).
    // lane l -> row 16c+(l>>2), dest slot (l&3); SOURCE k-chunk (l&3)^((l>>3)&3).
    const int qsrc = ((l & 3) ^ ((l >> 3) & 3)) * 8;
    const u16* aP[2]; const u16* bP;
    #pragma unroll
    for (int i = 0; i < 2; ++i) {
        int c = 2 * wid + i;
        int hr = base + tm * 256 + c * 16 + (l >> 2);
        if (hr > HROWS_ - 1) hr = HROWS_ - 1;    // clamp tail straddle (pad rows zeroed)
        aP[i] = Aglob + (size_t)hr * KDROW + qsrc;
    }
    {
        int cc = tn * 128 + wid * 16 + (l >> 2);
        bP = Bsrc + (size_t)cc * KDROW + qsrc;
    }

    f32x4 acc[4][4];
    #pragma unroll
    for (int mi = 0; mi < 4; ++mi)
        #pragma unroll
        for (int ni = 0; ni < 4; ++ni) acc[mi][ni] = (f32x4){0.f,0.f,0.f,0.f};

    auto stage = [&](int sb, int kof) {
        GLOAD16(aP[0] + kof, lds + sb + (2 * wid) * 1024);
        GLOAD16(aP[1] + kof, lds + sb + (2 * wid + 1) * 1024);
        GLOAD16(bP + kof, lds + sb + 16384 + wid * 1024);
    };

    // prologue: stage tiles 0,1; drain tile 0 only (tile 1's 3 loads stay in flight)
    stage(0, 0);
    stage(BUFB, 32);
    asm volatile("s_waitcnt vmcnt(3)" ::: "memory");
    __builtin_amdgcn_s_barrier();

    const int koff = ((((lr >> 1) & 3) ^ lg) << 4);
    int cb = 0, sb2 = 2 * BUFB, kofe = 64;
    for (int t = 0; t < NT; ++t) {
        bf16x8 a[4], b[4];
        #pragma unroll
        for (int mi = 0; mi < 4; ++mi)
            a[mi] = *(const bf16x8*)(lds + cb + (wm + mi * 16 + lr) * 64 + koff);
        #pragma unroll
        for (int ni = 0; ni < 4; ++ni)
            b[ni] = *(const bf16x8*)(lds + cb + 16384 + (wn + ni * 16 + lr) * 64 + koff);
        if (t < NT - 2) { stage(sb2, kofe); kofe += 32; }
        __builtin_amdgcn_s_setprio(1);
        #pragma unroll
        for (int mi = 0; mi < 4; ++mi)
            #pragma unroll
            for (int ni = 0; ni < 4; ++ni)
                acc[mi][ni] = __builtin_amdgcn_mfma_f32_16x16x32_bf16(a[mi], b[ni], acc[mi][ni], 0, 0, 0);
        __builtin_amdgcn_s_setprio(0);
        if (t < NT - 2)       { asm volatile("s_waitcnt vmcnt(3)" ::: "memory"); }
        else if (t == NT - 2) { asm volatile("s_waitcnt vmcnt(0)" ::: "memory"); }
        if (t < NT - 1) __builtin_amdgcn_s_barrier();
        cb += BUFB;  if (cb == 3 * BUFB)  cb = 0;
        sb2 += BUFB; if (sb2 == 3 * BUFB) sb2 = 0;
    }

    // ---- epilogue: C/D frag row = lg*4+j (lg here = l>>4 in 0..3), col = lr ----
    if (IS_G1) {
        const float* be = bias + e * F_;
        const int pad = ((cnt + 127) >> 7) << 7;
        #pragma unroll
        for (int mi = 0; mi < 4; ++mi) {
            #pragma unroll
            for (int j = 0; j < 4; ++j) {
                int rl = tm * 256 + wm + mi * 16 + lg * 4 + j;
                if (rl < pad) {
                    size_t srow = (size_t)(base + rl) * F_;
                    #pragma unroll
                    for (int ni = 0; ni < 4; ++ni) {
                        int f = tn * 128 + wn + ni * 16 + lr;
                        hOut[srow + f] = f2b(gelu_f(acc[mi][ni][j] + be[f]));
                    }
                }
            }
        }
    } else {
        const float* be = bias + e * D_;
        #pragma unroll
        for (int mi = 0; mi < 4; ++mi) {
            #pragma unroll
            for (int j = 0; j < 4; ++j) {
                int rl = tm * 256 + wm + mi * 16 + lg * 4 + j;
                if (rl < cnt) {
                    int tkn = idx_e[rl];
                    float cw = combine[tkn * E_ + e];
                    float* orow = out + (size_t)tkn * D_;
                    #pragma unroll
                    for (int ni = 0; ni < 4; ++ni) {
                        int d = tn * 128 + wn + ni * 16 + lr;
                        atomicAdd(&orow[d], cw * (acc[mi][ni][j] + be[d]));
                    }
                }
            }
        }
    }
}

__global__ void loss_kernel(const int* __restrict__ fcnt, const float* __restrict__ psum,
                            float* __restrict__ dst) {
    if (threadIdx.x == 0 && blockIdx.x == 0) {
        float loss = 0.f;
        for (int e = 0; e < E_; ++e) {
            float fs = 0.f, Ps = 0.f;
            for (int s = 0; s < 64; ++s) { fs += (float)fcnt[s * E_ + e]; Ps += psum[s * E_ + e]; }
            loss += (fs / (float)T_) * (Ps / (float)T_);
        }
        *dst = LBW_ * (float)E_ * loss;
    }
}

__global__ void sentinel_kernel(float* __restrict__ dst) {
    if (threadIdx.x == 0) dst[0] = -12345.0f;
}

extern "C" void kernel_launch(void* const* d_in, const int* in_sizes, int n_in,
                              void* d_out, int out_size, void* d_ws, size_t ws_size,
                              hipStream_t stream)
{
    const float* x  = (const float*)d_in[0];
    const float* ew = (const float*)d_in[1];
    const float* gw = (const float*)d_in[2];
    const float* gb = (const float*)d_in[3];
    const float* w1 = (const float*)d_in[4];
    const float* b1 = (const float*)d_in[5];
    const float* w2 = (const float*)d_in[6];
    const float* b2 = (const float*)d_in[7];
    float* out = (float*)d_out;

    char* ws = (char*)d_ws;
    size_t o = 0;
    u16* w1t = (u16*)(ws + o); o += (size_t)E_ * D_ * F_ * 2;
    u16* w2t = (u16*)(ws + o); o += (size_t)E_ * F_ * D_ * 2;
    u16* xb  = (u16*)(ws + o); o += (size_t)T_ * D_ * 2;
    u16* xg  = (u16*)(ws + o); o += (size_t)HROWS_ * D_ * 2;
    u16* h   = (u16*)(ws + o); o += (size_t)HROWS_ * F_ * 2;
    float* combine = (float*)(ws + o); o += (size_t)T_ * E_ * 4;
    int* idx = (int*)(ws + o); o += (size_t)E_ * T_ * 4;
    size_t zoff = o;
    int* cnt   = (int*)(ws + o); o += 128;
    int* fcnt  = (int*)(ws + o); o += 64 * E_ * 4;
    float* psum = (float*)(ws + o); o += 64 * E_ * 4;
    int* off   = (int*)(ws + o); o += 128;
    int* table = (int*)(ws + o); o += 512;
    int* ntab  = (int*)(ws + o); o += 128;
    const size_t ws_needed = o;

    if (ws_size < ws_needed) {
        hipMemsetAsync(d_out, 0, (size_t)out_size * sizeof(float), stream);
        sentinel_kernel<<<1, 64, 0, stream>>>(out + (size_t)out_size - 1);
        return;
    }

    hipMemsetAsync(ws + zoff, 0, ws_needed - zoff, stream);
    hipMemsetAsync(d_out, 0, (size_t)out_size * sizeof(float), stream);

    cvt_T_kernel<<<dim3(F_ / 64, D_ / 64, E_), 256, 0, stream>>>(w1, w1t, D_, F_);
    cvt_T_kernel<<<dim3(D_ / 64, F_ / 64, E_), 256, 0, stream>>>(w2, w2t, F_, D_);
    gate_kernel<<<T_, 64, 0, stream>>>(x, ew, gw, gb, xb, combine, idx, cnt, fcnt, psum);
    tiletab_kernel<<<1, 64, 0, stream>>>(cnt, off, table, ntab);
    gather_kernel<<<HROWS_ / 16, 256, 0, stream>>>(xb, idx, cnt, off, xg);
    // gemm1: K=1024 (NT=32), 256x128, NTN=32 -> ~2176 working blocks at 2/CU (~4.25 rounds)
    moe_gemm2c<32, 1024, 32, true><<<NTILE_MAX * 32, 512, 0, stream>>>(
        xg, w1t, b1, nullptr, idx, cnt, off, table, ntab, h, nullptr);
    // gemm2: K=4096 (NT=128), 256x128, NTN=8 -> ~544 working blocks at 2/CU (~1.06-2 rounds)
    moe_gemm2c<128, 4096, 8, false><<<NTILE_MAX * 8, 512, 0, stream>>>(
        h, w2t, b2, combine, idx, cnt, off, table, ntab, nullptr, out);
    loss_kernel<<<1, 64, 0, stream>>>(fcnt, psum, out + (size_t)out_size - 1);
}